// Round 9
// baseline (211.152 us; speedup 1.0000x reference)
//
#include <hip/hip_runtime.h>

#define D_FEAT 64
#define SRC_RANGES 4
#define SRC_RANGE_BITS 15          // 32768 nodes per range (4*32768 >= 100k)
#define SRC_CHUNKS 64

// ---------------- zero-fill (rocclr fillBuffer takes 43us for 663KB!) --------
__global__ void zero_kernel(int4* __restrict__ p, int n4) {
    int i = blockIdx.x * blockDim.x + threadIdx.x;
    if (i < n4) p[i] = make_int4(0, 0, 0, 0);
}

// ---------------- dst histogram + rank (counting-sort key) -------------------
// 8 edges/thread: doubles in-flight atomics per wave (latency-bound path).
// NOTE (R8): do NOT fuse this with the LDS histogram — 64KB static LDS caps
// occupancy for ALL blocks and halves atomic throughput (76us fused vs 43+10).
__global__ void dst_rank_kernel(const int* __restrict__ dst, int* __restrict__ deg_dst,
                                unsigned short* __restrict__ rank, int E) {
    int e8 = (blockIdx.x * blockDim.x + threadIdx.x) * 8;
    if (e8 + 7 < E) {
        int4 d0 = *(const int4*)(dst + e8);
        int4 d1 = *(const int4*)(dst + e8 + 4);
        ushort4 r0, r1;
        r0.x = (unsigned short)atomicAdd(&deg_dst[d0.x], 1);
        r0.y = (unsigned short)atomicAdd(&deg_dst[d0.y], 1);
        r0.z = (unsigned short)atomicAdd(&deg_dst[d0.z], 1);
        r0.w = (unsigned short)atomicAdd(&deg_dst[d0.w], 1);
        r1.x = (unsigned short)atomicAdd(&deg_dst[d1.x], 1);
        r1.y = (unsigned short)atomicAdd(&deg_dst[d1.y], 1);
        r1.z = (unsigned short)atomicAdd(&deg_dst[d1.z], 1);
        r1.w = (unsigned short)atomicAdd(&deg_dst[d1.w], 1);
        *(ushort4*)(rank + e8)     = r0;       // coalesced 8B stores
        *(ushort4*)(rank + e8 + 4) = r1;
    } else {
        for (int e = e8; e < E; ++e)
            rank[e] = (unsigned short)atomicAdd(&deg_dst[dst[e]], 1);
    }
}

// ---------------- src histogram: LDS-privatized, zero random global atomics --
__global__ void src_hist_kernel(const int* __restrict__ src,
                                unsigned int* __restrict__ packed, int E) {
    __shared__ unsigned int h[16384];          // 32768 x u16
    const int range = blockIdx.x & (SRC_RANGES - 1);
    const int chunk = blockIdx.x >> 2;
    const int lo = range << SRC_RANGE_BITS;
    for (int i = threadIdx.x; i < 16384; i += blockDim.x) h[i] = 0;
    __syncthreads();
    const int cs = (E + SRC_CHUNKS - 1) / SRC_CHUNKS;
    const int e0 = chunk * cs, e1 = min(e0 + cs, E);
    for (int e = e0 + threadIdx.x; e < e1; e += blockDim.x) {
        unsigned r = (unsigned)(src[e] - lo);
        if (r < 32768u)
            atomicAdd(&h[r >> 1], 1u << ((r & 1) << 4));
    }
    __syncthreads();
    for (int i = threadIdx.x; i < 16384; i += blockDim.x) {
        unsigned v = h[i];
        if (v) atomicAdd(&packed[(lo >> 1) + i], v);  // coalesced, skip-zero
    }
}

// ---------------- single-pass exclusive scan: decoupled lookback -------------
// (R5-verified). Block 0's aggregate IS its inclusive -> idx==0 spins on incl
// only, guaranteeing termination. Published +1 so 0 == "not ready".
__global__ void scan_kernel(const int* __restrict__ deg, int* __restrict__ row_start,
                            int* __restrict__ agg, int* __restrict__ incl, int N) {
    __shared__ int lds[1024];
    __shared__ int s_prev;
    const int t = threadIdx.x;
    const int c = blockIdx.x;
    const int i = c * 1024 + t;
    int v = (i < N) ? deg[i] : 0;
    lds[t] = v;
    __syncthreads();
    for (int off = 1; off < 1024; off <<= 1) {
        int x = (t >= off) ? lds[t - off] : 0;
        __syncthreads();
        lds[t] += x;
        __syncthreads();
    }
    const int local_incl = lds[t];
    const int total      = lds[1023];
    if (t == 0)
        __hip_atomic_store(&agg[c], total + 1, __ATOMIC_RELEASE, __HIP_MEMORY_SCOPE_AGENT);
    if (t < 64) {
        int prev = 0;
        if (c > 0) {
            int j = c - 1;
            while (true) {
                int idx = j - t;
                bool valid = (idx >= 0);
                int iv = 0, av = 0;
                if (valid) {
                    while (true) {
                        iv = __hip_atomic_load(&incl[idx], __ATOMIC_ACQUIRE,
                                               __HIP_MEMORY_SCOPE_AGENT);
                        if (iv) break;
                        if (idx > 0) {
                            av = __hip_atomic_load(&agg[idx], __ATOMIC_ACQUIRE,
                                                   __HIP_MEMORY_SCOPE_AGENT);
                            if (av) break;
                        }
                    }
                }
                unsigned long long m = __ballot(valid && (iv != 0));
                int contrib; bool done;
                if (m) {
                    int lstar = __ffsll((long long)m) - 1;
                    contrib = (t < lstar) ? (av - 1) : (t == lstar ? iv - 1 : 0);
                    done = true;
                } else {
                    contrib = valid ? (av - 1) : 0;
                    done = false;
                }
                #pragma unroll
                for (int off = 32; off >= 1; off >>= 1) contrib += __shfl_xor(contrib, off);
                prev += contrib;
                if (done) break;
                j -= 64;
            }
        }
        if (t == 0) {
            __hip_atomic_store(&incl[c], prev + total + 1, __ATOMIC_RELEASE,
                               __HIP_MEMORY_SCOPE_AGENT);
            s_prev = prev;
        }
    }
    __syncthreads();
    if (i < N) row_start[i] = s_prev + local_incl - v;
}

// ---------------- placement WITHOUT atomics (rank-based) ---------------------
__global__ void place_rank_kernel(const int* __restrict__ src, const int* __restrict__ dst,
                                  const unsigned short* __restrict__ rank,
                                  const unsigned int* __restrict__ packed_src,
                                  const int* __restrict__ row_start,
                                  int2* __restrict__ edges, int E) {
    int e = blockIdx.x * blockDim.x + threadIdx.x;
    if (e >= E) return;
    int s = src[e], d = dst[e];
    int pos = row_start[d] + (int)rank[e];
    unsigned pv = packed_src[s >> 1];
    int degs = (int)((pv >> ((s & 1) << 4)) & 0xffffu);
    float coef = rsqrtf((float)max(degs, 1));
    edges[pos] = make_int2(s, __float_as_int(coef));
}

// ---------------- gather-aggregate: 2 nodes per wave, 4 edges/slot -----------
__global__ void aggregate_kernel(const float* __restrict__ feat,
                                 const int2* __restrict__ edges,
                                 const int* __restrict__ row_start,
                                 const int* __restrict__ deg_dst,
                                 float* __restrict__ out, int N) {
    int w = blockIdx.x * (blockDim.x >> 6) + (threadIdx.x >> 6);
    int lane = threadIdx.x & 63;
    int n0 = 2 * w;
    int n1 = 2 * w + 1;
    if (n0 >= N) return;
    bool has1 = (n1 < N);
    int g = lane >> 4;       // edge slot (0..3)
    int q = lane & 15;       // dim quad (float4)
    int k0 = deg_dst[n0], b0 = row_start[n0];
    int k1 = has1 ? deg_dst[n1] : 0;
    int b1 = has1 ? row_start[n1] : 0;

    float4 acc0 = make_float4(0.f, 0.f, 0.f, 0.f);
    float4 acc1 = make_float4(0.f, 0.f, 0.f, 0.f);
    int kmax = max(k0, k1);
    for (int i0 = 0; i0 < kmax; i0 += 64) {
        int2 e0 = make_int2(0, 0), e1 = make_int2(0, 0);
        if (i0 + lane < k0) e0 = edges[b0 + i0 + lane];
        if (i0 + lane < k1) e1 = edges[b1 + i0 + lane];
        int kk = min(64, kmax - i0);
        for (int t4 = 0; t4 * 4 < kk; ++t4) {
            int ei = t4 * 4 + g;
            int   s0 = __shfl(e0.x, ei);
            float c0 = __shfl(__int_as_float(e0.y), ei);
            int   s1 = __shfl(e1.x, ei);
            float c1 = __shfl(__int_as_float(e1.y), ei);
            const float4 r0 = *(const float4*)(feat + (size_t)s0 * D_FEAT + q * 4);
            const float4 r1 = *(const float4*)(feat + (size_t)s1 * D_FEAT + q * 4);
            acc0.x += r0.x * c0; acc0.y += r0.y * c0;
            acc0.z += r0.z * c0; acc0.w += r0.w * c0;
            acc1.x += r1.x * c1; acc1.y += r1.y * c1;
            acc1.z += r1.z * c1; acc1.w += r1.w * c1;
        }
    }
    #pragma unroll
    for (int m = 16; m <= 32; m <<= 1) {
        acc0.x += __shfl_xor(acc0.x, m); acc0.y += __shfl_xor(acc0.y, m);
        acc0.z += __shfl_xor(acc0.z, m); acc0.w += __shfl_xor(acc0.w, m);
        acc1.x += __shfl_xor(acc1.x, m); acc1.y += __shfl_xor(acc1.y, m);
        acc1.z += __shfl_xor(acc1.z, m); acc1.w += __shfl_xor(acc1.w, m);
    }
    if (g == 0) {
        float nd0 = rsqrtf((float)max(k0, 1));
        acc0.x *= nd0; acc0.y *= nd0; acc0.z *= nd0; acc0.w *= nd0;
        *(float4*)(out + (size_t)n0 * D_FEAT + q * 4) = acc0;
        if (has1) {
            float nd1 = rsqrtf((float)max(k1, 1));
            acc1.x *= nd1; acc1.y *= nd1; acc1.z *= nd1; acc1.w *= nd1;
            *(float4*)(out + (size_t)n1 * D_FEAT + q * 4) = acc1;
        }
    }
}

extern "C" void kernel_launch(void* const* d_in, const int* in_sizes, int n_in,
                              void* d_out, int out_size, void* d_ws, size_t ws_size,
                              hipStream_t stream) {
    const float* feat = (const float*)d_in[0];
    const int*   src  = (const int*)d_in[1];
    const int*   dst  = (const int*)d_in[2];
    float* out = (float*)d_out;

    const int E = in_sizes[1];
    const int N = in_sizes[0] / D_FEAT;

    // layout: [zeroed] packed_src(65536 u32) deg_dst(N) agg(128) incl(128)
    //         [no init] row_start(N) edges(int2 x E) rank(ushort x E)
    unsigned int* packed_src = (unsigned int*)d_ws;          // 65536 (covers 4 ranges)
    int* deg_dst   = (int*)(packed_src + 65536);             // N
    int* agg       = deg_dst + N;                            // 128
    int* incl      = agg + 128;                              // 128
    const int zero_ints = 65536 + N + 256;
    const int zero_i4   = (zero_ints + 3) / 4;               // int4 count (pad-safe)
    int* row_start = (int*)d_ws + zero_i4 * 4;               // N (starts after pad)
    int2* edges    = (int2*)(row_start + N);                 // E
    unsigned short* rank = (unsigned short*)(edges + E);     // E
    (void)ws_size;

    zero_kernel<<<(zero_i4 + 255) / 256, 256, 0, stream>>>((int4*)d_ws, zero_i4);

    dst_rank_kernel<<<(E / 8 + 255) / 256, 256, 0, stream>>>(dst, deg_dst, rank, E);
    src_hist_kernel<<<SRC_RANGES * SRC_CHUNKS, 256, 0, stream>>>(src, packed_src, E);
    scan_kernel<<<(N + 1023) / 1024, 1024, 0, stream>>>(deg_dst, row_start, agg, incl, N);
    place_rank_kernel<<<(E + 255) / 256, 256, 0, stream>>>(src, dst, rank, packed_src,
                                                           row_start, edges, E);
    // 2 nodes per wave, 4 waves per block -> 8 nodes/block
    aggregate_kernel<<<(N + 7) / 8, 256, 0, stream>>>(feat, edges, row_start,
                                                      deg_dst, out, N);
}